// Round 10
// baseline (191.845 us; speedup 1.0000x reference)
//
#include <hip/hip_runtime.h>

// Problem constants
#define BQ   2
#define SQ   2048
#define DIMQ 1024
#define HQ   16
#define HDQ  64
#define KQ   64
#define QKV_STRIDE (3 * DIMQ)

typedef __attribute__((ext_vector_type(8))) short short8;   // 8 bf16 (4 VGPRs)
typedef __attribute__((ext_vector_type(4))) float floatx4;  // 4 fp32 acc
typedef __attribute__((ext_vector_type(2))) float float2v;  // packed fp32 pair

typedef const __attribute__((address_space(1))) unsigned short* gas_t;
typedef __attribute__((address_space(3))) unsigned short* las_t;

#define LOG2E 1.4426950408889634f

__device__ __forceinline__ unsigned short f2b(float f) {
    union { float f; unsigned int u; } x; x.f = f;
    unsigned int r = x.u + 0x7fffu + ((x.u >> 16) & 1u);   // RNE
    return (unsigned short)(r >> 16);
}
__device__ __forceinline__ float b2f(unsigned short u) {
    union { unsigned int u; float f; } x; x.u = ((unsigned int)u) << 16;
    return x.f;
}
// Unpack a dword holding 2 bf16 -> float2v {lo, hi}
__device__ __forceinline__ float2v unpk(unsigned int d) {
    union { unsigned int u; float f; } lo, hi;
    lo.u = d << 16;
    hi.u = d & 0xffff0000u;
    float2v r; r[0] = lo.f; r[1] = hi.f;
    return r;
}

// ---------------------------------------------------------------------------
// Fused fp32 -> bf16 cast over three buffers (x, w_qkv, w_out), float4 lanes.
__global__ __launch_bounds__(256) void cast3_f32_bf16(const float* __restrict__ s0, unsigned short* __restrict__ d0, int n0,
                                                      const float* __restrict__ s1, unsigned short* __restrict__ d1, int n1,
                                                      const float* __restrict__ s2, unsigned short* __restrict__ d2, int n2) {
    int i = blockIdx.x * blockDim.x + threadIdx.x;
    const float* s; unsigned short* d;
    if (i < n0)                { s = s0; d = d0; }
    else if (i < n0 + n1)      { s = s1; d = d1; i -= n0; }
    else if (i < n0 + n1 + n2) { s = s2; d = d2; i -= n0 + n1; }
    else return;
    float4 v = ((const float4*)s)[i];
    ushort4 o;
    o.x = f2b(v.x); o.y = f2b(v.y); o.z = f2b(v.z); o.w = f2b(v.w);
    ((ushort4*)d)[i] = o;
}

// ---------------------------------------------------------------------------
// C[M,N] = A[M,K] @ B[N,K]^T + bias[N]   (A,B bf16 row-major; C fp32 or bf16)
// BMxBN tile, BK=64 (32 MFMAs between barriers), 256 threads = 4 waves
// (2x2 of BM/2 x BN/2), 16x16x32 MFMA. XOR k-chunk swizzle on the global side.
template <int BM, int BN, typename CT>
__global__ __launch_bounds__(256) void gemm_bf16_nt(const unsigned short* __restrict__ A,
                                                    const unsigned short* __restrict__ B,
                                                    const float* __restrict__ bias,
                                                    CT* __restrict__ C,
                                                    int M, int N, int K) {
    constexpr int MI = BM / 32;          // 16-row mfma tiles per wave
    constexpr int NJ = BN / 32;          // 16-col mfma tiles per wave
    __shared__ unsigned short As[BM * 64];
    __shared__ unsigned short Bs[BN * 64];

    const int tid  = threadIdx.x;
    const int lane = tid & 63;
    const int wv   = tid >> 6;            // 0..3
    const int wm   = (wv >> 1) * (BM / 2);
    const int wn   = (wv & 1) * (BN / 2);
    const int fr   = lane & 15;           // fragment row (m or n)
    const int fq   = lane >> 4;           // quad -> k segment (8 elems)

    const int m0 = blockIdx.y * BM;
    const int n0 = blockIdx.x * BN;

    floatx4 acc[MI][NJ];
#pragma unroll
    for (int i = 0; i < MI; ++i)
#pragma unroll
        for (int j = 0; j < NJ; ++j) acc[i][j] = (floatx4)(0.f);

    const unsigned short* Ab = A + (size_t)m0 * K;
    const unsigned short* Bb = B + (size_t)n0 * K;

    for (int k0 = 0; k0 < K; k0 += 64) {
#pragma unroll
        for (int c = 0; c < (BM + BN) * 8; c += 256) {
            const int cc = c + tid;
            if (cc < BM * 8) {
                const int row = cc >> 3;
                const int kc  = ((cc & 7) ^ (row & 7)) << 3;
                __builtin_amdgcn_global_load_lds(
                    (gas_t)(Ab + (size_t)row * K + k0 + kc),
                    (las_t)&As[cc * 8], 16, 0, 0);
            } else {
                const int c2  = cc - BM * 8;
                const int row = c2 >> 3;
                const int kc  = ((c2 & 7) ^ (row & 7)) << 3;
                __builtin_amdgcn_global_load_lds(
                    (gas_t)(Bb + (size_t)row * K + k0 + kc),
                    (las_t)&Bs[c2 * 8], 16, 0, 0);
            }
        }
        __syncthreads();

#pragma unroll
        for (int ks = 0; ks < 2; ++ks) {
            short8 af[MI], bf[NJ];
#pragma unroll
            for (int i = 0; i < MI; ++i) {
                const int row = wm + i * 16 + fr;
                const int pos = (ks * 4 + fq) ^ (row & 7);
                af[i] = *(const short8*)&As[row * 64 + pos * 8];
            }
#pragma unroll
            for (int j = 0; j < NJ; ++j) {
                const int row = wn + j * 16 + fr;
                const int pos = (ks * 4 + fq) ^ (row & 7);
                bf[j] = *(const short8*)&Bs[row * 64 + pos * 8];
            }
#pragma unroll
            for (int i = 0; i < MI; ++i)
#pragma unroll
                for (int j = 0; j < NJ; ++j)
                    acc[i][j] = __builtin_amdgcn_mfma_f32_16x16x32_bf16(af[i], bf[j], acc[i][j], 0, 0, 0);
        }
        __syncthreads();
    }

    // Epilogue. D mapping: col = lane&15 (=fr), row = (lane>>4)*4 + reg (=fq*4+r)
    float bv[NJ];
#pragma unroll
    for (int j = 0; j < NJ; ++j) bv[j] = bias[n0 + wn + j * 16 + fr];
#pragma unroll
    for (int i = 0; i < MI; ++i) {
#pragma unroll
        for (int r = 0; r < 4; ++r) {
            const size_t row = (size_t)(m0 + wm + i * 16 + fq * 4 + r);
#pragma unroll
            for (int j = 0; j < NJ; ++j) {
                const float v = acc[i][j][r] + bv[j];
                if constexpr (sizeof(CT) == 2)
                    C[row * N + n0 + wn + j * 16 + fr] = (CT)f2b(v);
                else
                    C[row * N + n0 + wn + j * 16 + fr] = (CT)v;
            }
        }
    }
}

// ---------------------------------------------------------------------------
// Attention (R5/R8 structure, VALU-bound) with packed-fp32 (v_pk_fma_f32)
// inner math and exp2-domain softmax (log2e folded into the score scale).
// One block per (b,q); 256 threads; online softmax, fused K+V gather loop.
// Thread t: j-group g = t>>7, head h = (t&127)>>3, dims d0 = (t&7)*8 (16 B).
// qkv: bf16 [B, S, 3, H, HD]. out: bf16 [B, S, H*HD].
__global__ __launch_bounds__(256) void attn_kernel(const unsigned short* __restrict__ qkv,
                                                   const int* __restrict__ routes,
                                                   unsigned short* __restrict__ out) {
    __shared__ int   r_s[KQ];
    __shared__ float m_s[128], l_s[128];
    __shared__ float o_part[8][128];

    const int t  = threadIdx.x;           // 0..255
    const int id = blockIdx.x;
    // XCD-contiguity swizzle: same XCD (id%8) gets a contiguous bq range.
    const int bq = (id & 7) * 512 + (id >> 3);
    const int b  = bq >> 11;
    const int q  = bq & 2047;

    if (t < KQ) r_s[t] = routes[q * KQ + t];

    const int g  = t >> 7;                // j-group: 0 or 1
    const int th = t & 127;
    const int h  = th >> 3;               // head
    const int d0 = (t & 7) * 8;           // dim offset within head

    // Q fragment as 4 packed float2 (scale folded in: s_log2 = p*(0.125*log2e))
    float2v qf2[4];
    {
        const uint4 q8 = *(const uint4*)&qkv[((size_t)bq * 3) * DIMQ + h * HDQ + d0];
        qf2[0] = unpk(q8.x); qf2[1] = unpk(q8.y);
        qf2[2] = unpk(q8.z); qf2[3] = unpk(q8.w);
    }
    __syncthreads();

    const unsigned short* baseK = qkv + ((size_t)b * SQ * 3 + 1) * DIMQ + h * HDQ + d0;
    const unsigned short* baseV = qkv + ((size_t)b * SQ * 3 + 2) * DIMQ + h * HDQ + d0;

    float m = -1e30f, l = 0.f;            // m, l tracked in log2 domain
    float2v o2[4];
#pragma unroll
    for (int e = 0; e < 4; ++e) o2[e] = (float2v)(0.f);

#pragma unroll 4
    for (int jj = 0; jj < KQ / 2; ++jj) {
        const int j = jj * 2 + g;
        const size_t roff = (size_t)r_s[j] * QKV_STRIDE;
        const uint4 kx = *(const uint4*)(baseK + roff);
        const uint4 vx = *(const uint4*)(baseV + roff);

        // K-dot via packed fma
        float2v dot = qf2[0] * unpk(kx.x);
        dot = __builtin_elementwise_fma(qf2[1], unpk(kx.y), dot);
        dot = __builtin_elementwise_fma(qf2[2], unpk(kx.z), dot);
        dot = __builtin_elementwise_fma(qf2[3], unpk(kx.w), dot);
        float p = dot[0] + dot[1];
        p += __shfl_xor(p, 1, 64);
        p += __shfl_xor(p, 2, 64);
        p += __shfl_xor(p, 4, 64);
        const float s  = p * (0.125f * LOG2E);       // log2-domain score
        const float mn = fmaxf(m, s);
        const float al = exp2f(m - mn);
        const float pe = exp2f(s - mn);
        l = l * al + pe;
        m = mn;

        // V accumulate via packed mul/fma
        float2v al2; al2[0] = al; al2[1] = al;
        float2v pe2; pe2[0] = pe; pe2[1] = pe;
        o2[0] = __builtin_elementwise_fma(o2[0], al2, pe2 * unpk(vx.x));
        o2[1] = __builtin_elementwise_fma(o2[1], al2, pe2 * unpk(vx.y));
        o2[2] = __builtin_elementwise_fma(o2[2], al2, pe2 * unpk(vx.z));
        o2[3] = __builtin_elementwise_fma(o2[3], al2, pe2 * unpk(vx.w));
    }

    // Merge the two j-groups (online-softmax state merge, log2 domain), store.
    if (g == 1) {
        m_s[th] = m; l_s[th] = l;
#pragma unroll
        for (int e = 0; e < 8; ++e) o_part[e][th] = o2[e >> 1][e & 1];
    }
    __syncthreads();
    if (g == 0) {
        const float m1 = m_s[th], l1 = l_s[th];
        const float mm = fmaxf(m, m1);
        const float a0 = exp2f(m - mm);
        const float a1 = exp2f(m1 - mm);
        const float inv = 1.0f / (l * a0 + l1 * a1);
        float oo[8];
#pragma unroll
        for (int e = 0; e < 8; ++e)
            oo[e] = (o2[e >> 1][e & 1] * a0 + o_part[e][th] * a1) * inv;
        ushort4 lo, hi;
        lo.x = f2b(oo[0]); lo.y = f2b(oo[1]); lo.z = f2b(oo[2]); lo.w = f2b(oo[3]);
        hi.x = f2b(oo[4]); hi.y = f2b(oo[5]); hi.z = f2b(oo[6]); hi.w = f2b(oo[7]);
        ushort4* dst = (ushort4*)&out[(size_t)bq * DIMQ + h * HDQ + d0];
        dst[0] = lo; dst[1] = hi;
    }
}

// ---------------------------------------------------------------------------
extern "C" void kernel_launch(void* const* d_in, const int* in_sizes, int n_in,
                              void* d_out, int out_size, void* d_ws, size_t ws_size,
                              hipStream_t stream) {
    const float* x      = (const float*)d_in[0];
    const float* w_qkv  = (const float*)d_in[1];
    const float* b_qkv  = (const float*)d_in[2];
    const float* w_out  = (const float*)d_in[3];
    const float* b_out  = (const float*)d_in[4];
    const int*   routes = (const int*)d_in[5];
    float* out = (float*)d_out;

    // ws layout (bytes): [0,24M) qkv bf16 | [24M,..) xb / attnb (aliased)
    //                    then w_qkv_bf16, w_out_bf16
    char* ws = (char*)d_ws;
    unsigned short* qkvb  = (unsigned short*)ws;                      // 24 MB
    unsigned short* xb    = (unsigned short*)(ws + 25165824);         // 8.4 MB
    unsigned short* attnb = xb;                                       // aliased
    unsigned short* wqb   = (unsigned short*)(ws + 33554432);         // 6.3 MB
    unsigned short* wob   = (unsigned short*)(ws + 39845888);         // 2.1 MB

    const int M = BQ * SQ;   // 4096
    dim3 blk(256);

    // Fused casts (x, w_qkv, w_out), float4 per thread
    {
        const int n0 = M * DIMQ / 4, n1 = 3 * DIMQ * DIMQ / 4, n2 = DIMQ * DIMQ / 4;
        cast3_f32_bf16<<<(n0 + n1 + n2 + 255) / 256, blk, 0, stream>>>(
            x, xb, n0, w_qkv, wqb, n1, w_out, wob, n2);
    }

    // 1) QKV projection -> bf16 qkv [B,S,3,H,HD]  (BK=64, 32 MFMAs/barrier)
    gemm_bf16_nt<128, 128, unsigned short><<<dim3(3 * DIMQ / 128, M / 128), blk, 0, stream>>>(
        xb, wqb, b_qkv, qkvb, M, 3 * DIMQ, DIMQ);

    // 2) Routed attention: fused online-softmax, packed-fp32 math
    attn_kernel<<<BQ * SQ, blk, 0, stream>>>(qkvb, routes, attnb);

    // 3) Output projection -> fp32 final output (128x64 tiles: 512 blocks)
    gemm_bf16_nt<128, 64, float><<<dim3(DIMQ / 64, M / 128), blk, 0, stream>>>(
        attnb, wob, b_out, out, M, DIMQ, DIMQ);
}